// Round 2
// baseline (290.136 us; speedup 1.0000x reference)
//
#include <hip/hip_runtime.h>
#include <stdint.h>

// BitLinear: y = (int8(x) @ unpack2bit(Wp)^T) * amax/(127*ws) + bias
// M=16384 tokens, K=2048, N=2048. Integer GEMM.
// R4: GEMM core switched to mfma_i32_32x32x32_i8 (4404 TOPS ubench vs 3944
//     for 16x16x64; half the MFMA issue slots). Full fragment reuse:
//     A read once per MH phase (16 b128/tile), B held in two register sets
//     b0/b1 read once per NH (8 b128/tile) -> 24 ds_read_b128 per K-tile
//     per wave vs 32 in R3. Same 256x256 tile, 8-wave, BK=128B, 4-phase
//     counted-vmcnt pipeline (waits 4/4/6/4, never 0 in main loop), same
//     XOR-swizzled LDS (slot = chunk ^ (row&7)) staged via pre-swizzled
//     global source, same XCD-aware block swizzle.

typedef __attribute__((ext_vector_type(4)))  int int4v;
typedef __attribute__((ext_vector_type(16))) int int16v;

#define GLOBAL_AS __attribute__((address_space(1)))
#define LDS_AS    __attribute__((address_space(3)))

static constexpr int MK = 2048;   // K (inner dim)
static constexpr int NN = 2048;   // out features
static constexpr int MM = 16384;  // tokens

// ---------------- activation quant: one block per token row (unchanged) ----
__global__ void quant_kernel(const float* __restrict__ x,
                             const float* __restrict__ wscale,
                             signed char* __restrict__ xq,
                             float* __restrict__ rf) {
    const int m = blockIdx.x;
    const int t = threadIdx.x;
    const float4* xr = (const float4*)(x + (size_t)m * MK);  // 512 float4/row
    float4 v0 = xr[t];
    float4 v1 = xr[t + 256];
    float amax = fmaxf(fmaxf(fabsf(v0.x), fabsf(v0.y)),
                       fmaxf(fabsf(v0.z), fabsf(v0.w)));
    amax = fmaxf(amax, fmaxf(fmaxf(fabsf(v1.x), fabsf(v1.y)),
                             fmaxf(fabsf(v1.z), fabsf(v1.w))));
    #pragma unroll
    for (int off = 32; off >= 1; off >>= 1)
        amax = fmaxf(amax, __shfl_xor(amax, off));
    __shared__ float smax[4];
    if ((t & 63) == 0) smax[t >> 6] = amax;
    __syncthreads();
    float a0 = fmaxf(fmaxf(smax[0], smax[1]), fmaxf(smax[2], smax[3]));
    a0 = fmaxf(a0, 1e-5f);
    const float scale = 127.0f / a0;
    if (t == 0) rf[m] = a0 / (127.0f * wscale[0]);

    auto q = [&](float f) -> int {
        float r = rintf(f * scale);        // round-half-to-even
        r = fminf(fmaxf(r, -128.0f), 127.0f);
        return (int)r;
    };
    int p0 = (q(v0.x) & 255) | ((q(v0.y) & 255) << 8) |
             ((q(v0.z) & 255) << 16) | ((q(v0.w) & 255) << 24);
    int p1 = (q(v1.x) & 255) | ((q(v1.y) & 255) << 8) |
             ((q(v1.z) & 255) << 16) | ((q(v1.w) & 255) << 24);
    int* xqr = (int*)(xq + (size_t)m * MK);
    xqr[t]       = p0;
    xqr[t + 256] = p1;
}

// ---------------- weight unpack (unchanged) --------------------------------
__global__ void unpack_kernel(const int* __restrict__ packed,
                              signed char* __restrict__ W) {
    const int idx = blockIdx.x * 256 + threadIdx.x;   // 0 .. 512*512
    const int r  = idx >> 9;        // packed row
    const int kq = idx & 511;       // k/4
    const int4 p = ((const int4*)packed)[idx];        // 4 consecutive k
    int* Wi = (int*)W;              // 512 ints per W row
    #pragma unroll
    for (int i = 0; i < 4; i++) {
        const int sh = 2 * i;
        int b0 = ((((p.x >> sh) & 3) - 1) & 255);
        int b1 = ((((p.y >> sh) & 3) - 1) & 255);
        int b2 = ((((p.z >> sh) & 3) - 1) & 255);
        int b3 = ((((p.w >> sh) & 3) - 1) & 255);
        Wi[(i * 512 + r) * 512 + kq] = b0 | (b1 << 8) | (b2 << 16) | (b3 << 24);
    }
}

// ---------------- int8 GEMM: 256x256 tile, 4-phase, 32x32x32 core ----------
// LDS (128 KiB): buf{0,1} x [A: 32KiB | B: 32KiB]. Stage-half h (16 KiB)
// holds 128 rows linearly (128 B/row); logical 16B chunk c of in-half row rw
// sits at slot c ^ (rw&7). A halves stripe at 64 rows (h == MH quadrant for
// both wm bands), B halves at 32 rows (h == NH quadrant for all wn).
#define WAITV(N) asm volatile("s_waitcnt vmcnt(" #N ")" ::: "memory")
#define BAR() do { __builtin_amdgcn_s_barrier(); \
                   __builtin_amdgcn_sched_barrier(0); } while (0)

__device__ __forceinline__ void stage_half(const signed char* __restrict__ src,
                                           int row0, int k0, int h, int ss,
                                           unsigned char* plane,
                                           int wave, int lane) {
    // lane writes LDS at (wave*2+j)*1024 + lane*16 -> in-half row rw, slot
    // lane&7. Fetch the logical chunk belonging in that slot:
    // c = (lane&7) ^ (rw&7), and rw&7 == lane>>3 for all groups.
    const int csrc = (((lane & 7) ^ (lane >> 3)) << 4);
    #pragma unroll
    for (int j = 0; j < 2; ++j) {
        const int rw = wave * 16 + j * 8 + (lane >> 3);          // 0..127
        const int r  = (rw & ((1 << ss) - 1)) + (h << ss)
                     + ((rw >> ss) << (ss + 1));                 // tile row
        const signed char* ga = src + (size_t)(row0 + r) * MK + k0 + csrc;
        __builtin_amdgcn_global_load_lds((const GLOBAL_AS void*)ga,
            (LDS_AS void*)(plane + (h << 14) + (wave * 2 + j) * 1024),
            16, 0, 0);
    }
}

// fragment reads (all indices compile-time after unroll)
#define RD_A(MH)                                                               \
  _Pragma("unroll")                                                            \
  for (int mt = 0; mt < 2; ++mt)                                               \
    _Pragma("unroll")                                                          \
    for (int ks = 0; ks < 4; ++ks)                                             \
      a[mt][ks] = *(const int4v*)(shp + cb + (MH)*16384 + arow + mt*4096       \
                                  + cbyte[ks]);

#define RD_B(NH, breg)                                                         \
  _Pragma("unroll")                                                            \
  for (int ks = 0; ks < 4; ++ks)                                               \
    breg[ks] = *(const int4v*)(shp + cb + brow + (NH)*16384 + cbyte[ks]);

#define MFM(MH, NH, breg)                                                      \
  do {                                                                         \
    __builtin_amdgcn_s_setprio(1);                                             \
    _Pragma("unroll")                                                          \
    for (int mt = 0; mt < 2; ++mt)                                             \
      _Pragma("unroll")                                                        \
      for (int ks = 0; ks < 4; ++ks)                                           \
        acc[(MH)*2+mt][NH] = __builtin_amdgcn_mfma_i32_32x32x32_i8(            \
            a[mt][ks], breg[ks], acc[(MH)*2+mt][NH], 0, 0, 0);                 \
    __builtin_amdgcn_s_setprio(0);                                             \
  } while (0)

__global__ void __launch_bounds__(512, 2)
gemm_kernel(const signed char* __restrict__ xq,   // [M][K]
            const signed char* __restrict__ W,    // [N][K]
            const float* __restrict__ rf,         // [M]
            const float* __restrict__ bias,       // [N]
            float* __restrict__ out) {            // [M][N]
    __shared__ __attribute__((aligned(16))) unsigned char sh[131072];
    unsigned char* shp = sh;

    const int tid  = threadIdx.x;
    const int wave = tid >> 6;
    const int lane = tid & 63;
    const int wm = wave >> 2;          // 0..1: wave's 128-row M band
    const int wn = wave & 3;           // 0..3: wave's 64-col N band

    // XCD-aware swizzle: 512 blocks = 8 XCDs x 64 contiguous chunks
    const int bs = ((blockIdx.x & 7) << 6) | (blockIdx.x >> 3);
    const int m0 = (bs >> 3) << 8;     // 64 M-tiles
    const int n0 = (bs & 7) << 8;      // 8  N-tiles

    // 32x32x32 fragment addressing: lane holds row ar = lane&31,
    // K-chunk (ks*2 + hl) of 16B, hl = lane>>5. Swizzled slot = c ^ (ar&7).
    const int ar = lane & 31, hl = lane >> 5;
    int cbyte[4];
    #pragma unroll
    for (int ks = 0; ks < 4; ++ks)
        cbyte[ks] = ((((ks << 1) | hl) ^ (ar & 7)) << 4);
    const int arow = (wm * 64 + ar) * 128;          // + MH*16384 + mt*4096
    const int brow = 32768 + (wn * 32 + ar) * 128;  // + NH*16384

    int4v a[2][4], b0[4], b1[4];
    int16v acc[4][2] = {};   // [MH*2+mt][NH]

    // prologue: stage tile 0 into buf0 in first-need order
    stage_half(xq, m0, 0, 0, 6, shp,         wave, lane);  // A mh0
    stage_half(W,  n0, 0, 0, 5, shp + 32768, wave, lane);  // B nh0
    stage_half(W,  n0, 0, 1, 5, shp + 32768, wave, lane);  // B nh1
    stage_half(xq, m0, 0, 1, 6, shp,         wave, lane);  // A mh1
    WAITV(4);
    BAR();

    #pragma unroll 1
    for (int t = 0; t < 15; ++t) {
        const int cb = (t & 1) << 16;       // current buffer
        const int nb = cb ^ 65536;          // next buffer
        const int k1 = (t + 1) << 7;

        RD_A(0); RD_B(0, b0);
        stage_half(xq, m0, k1, 0, 6, shp + nb,         wave, lane);
        WAITV(4); BAR();
        MFM(0, 0, b0);

        RD_B(1, b1);
        stage_half(W,  n0, k1, 0, 5, shp + nb + 32768, wave, lane);
        WAITV(4); BAR();
        MFM(0, 1, b1);

        RD_A(1);
        stage_half(W,  n0, k1, 1, 5, shp + nb + 32768, wave, lane);
        WAITV(6); BAR();
        MFM(1, 0, b0);

        stage_half(xq, m0, k1, 1, 6, shp + nb,         wave, lane);
        WAITV(4); BAR();
        MFM(1, 1, b1);
    }
    {   // tail tile 15 (buf1): no prefetch, drain 2 -> 0
        const int cb = 65536;
        RD_A(0); RD_B(0, b0);
        WAITV(2); BAR();
        MFM(0, 0, b0);

        RD_B(1, b1);
        WAITV(0); BAR();
        MFM(0, 1, b1);

        RD_A(1);
        BAR();
        MFM(1, 0, b0);

        BAR();
        MFM(1, 1, b1);
    }

    // epilogue: 32x32 C/D map col=lane&31, row=(reg&3)+8*(reg>>2)+4*(lane>>5)
    const int nb0 = n0 + wn * 64 + ar;
    const float bva = bias[nb0];
    const float bvb = bias[nb0 + 32];
    #pragma unroll
    for (int MH = 0; MH < 2; ++MH) {
        #pragma unroll
        for (int mt = 0; mt < 2; ++mt) {
            const int mbase = m0 + wm * 128 + MH * 64 + mt * 32 + hl * 4;
            #pragma unroll
            for (int q = 0; q < 4; ++q) {
                #pragma unroll
                for (int rr = 0; rr < 4; ++rr) {
                    const int m = mbase + q * 8 + rr;
                    const float frm = rf[m];
                    float* orow = out + (size_t)m * NN;
                    orow[nb0]      = (float)acc[MH*2+mt][0][q*4+rr] * frm + bva;
                    orow[nb0 + 32] = (float)acc[MH*2+mt][1][q*4+rr] * frm + bvb;
                }
            }
        }
    }
}

extern "C" void kernel_launch(void* const* d_in, const int* in_sizes, int n_in,
                              void* d_out, int out_size, void* d_ws, size_t ws_size,
                              hipStream_t stream) {
    const float* x      = (const float*)d_in[0];
    const int*   packed = (const int*)d_in[1];
    const float* wscale = (const float*)d_in[2];
    const float* bias   = (const float*)d_in[3];
    float* out = (float*)d_out;

    // workspace: xq [16384*2048] i8 | W [2048*2048] i8 | rf [16384] f32
    signed char* xq = (signed char*)d_ws;
    signed char* W  = xq + (size_t)MM * MK;
    float*       rf = (float*)(W + (size_t)NN * MK);

    quant_kernel<<<MM, 256, 0, stream>>>(x, wscale, xq, rf);
    unpack_kernel<<<(512 * 512) / 256, 256, 0, stream>>>(packed, W);
    gemm_kernel<<<dim3(512), 512, 0, stream>>>(xq, W, rf, bias, out);
}